// Round 1
// baseline (774.835 us; speedup 1.0000x reference)
//
#include <hip/hip_runtime.h>

#define N 8192
#define FIN 128
#define FOUT 64
#define ALPHA 0.2f

// Broadcast lane `l`'s value of v to all lanes (uniform l -> v_readlane, SGPR result)
static __device__ __forceinline__ float lane_bcast(float v, int l) {
    return __uint_as_float(__builtin_amdgcn_readlane(__float_as_uint(v), l));
}

// K1: Wh = x @ W  [N,FOUT];  Wh1 = Wh @ a[:FOUT];  Wh2 = Wh @ a[FOUT:]
// grid: N/4 blocks x 256 threads. thread t: row = bid*4 + t/64, f = t%64 (one wave per row-group)
__global__ __launch_bounds__(256) void gat_proj(const float* __restrict__ x,
                                                const float* __restrict__ W,
                                                const float* __restrict__ a,
                                                float* __restrict__ Wh,
                                                float* __restrict__ Wh1,
                                                float* __restrict__ Wh2) {
    const int t = threadIdx.x;
    const int f = t & 63;
    const int rl = t >> 6;                 // 0..3, == wave id
    const int row = blockIdx.x * 4 + rl;
    const float* __restrict__ xr = x + (size_t)row * FIN;

    float acc = 0.f;
    // 128-deep dot product; x row elements are wave-uniform broadcast loads,
    // W[k*64+f] is a coalesced 256B load per k. float4 on x to cut issue count.
    const float4* __restrict__ x4 = (const float4*)xr;
    #pragma unroll 8
    for (int k4 = 0; k4 < FIN / 4; ++k4) {
        float4 xv = x4[k4];
        int k = k4 * 4;
        acc = fmaf(xv.x, W[(k + 0) * FOUT + f], acc);
        acc = fmaf(xv.y, W[(k + 1) * FOUT + f], acc);
        acc = fmaf(xv.z, W[(k + 2) * FOUT + f], acc);
        acc = fmaf(xv.w, W[(k + 3) * FOUT + f], acc);
    }
    Wh[(size_t)row * FOUT + f] = acc;

    // rank-1 projections, wave-64 butterfly reduce
    float s1 = acc * a[f];
    float s2 = acc * a[FOUT + f];
    #pragma unroll
    for (int off = 32; off > 0; off >>= 1) {
        s1 += __shfl_xor(s1, off, 64);
        s2 += __shfl_xor(s2, off, 64);
    }
    if (f == 0) {
        Wh1[row] = s1;
        Wh2[row] = s2;
    }
}

// K2: fused masked-softmax attention + aggregation + ELU.
// grid: N/16 blocks x 256 threads (4 waves). Wave g owns rows {base+g, +4, +8, +12}
// entirely (all j), so den needs only an intra-wave reduction at the end.
// No-max softmax: scores are O(+-8), exp stays in fp32 range comfortably.
__global__ __launch_bounds__(256) void gat_attn(const int* __restrict__ adj,
                                                const float* __restrict__ Wh,
                                                const float* __restrict__ Wh1,
                                                const float* __restrict__ Wh2,
                                                float* __restrict__ out) {
    const int t = threadIdx.x;
    const int lane = t & 63;               // feature index in phase B
    const int g = t >> 6;                  // wave id 0..3
    const int rowbase = blockIdx.x * 16;

    int r[4];
    float wh1[4], acc[4], den[4];
    #pragma unroll
    for (int q = 0; q < 4; ++q) {
        r[q] = rowbase + g + 4 * q;
        wh1[q] = Wh1[r[q]];
        acc[q] = 0.f;
        den[q] = 0.f;
    }

    for (int jb = 0; jb < N; jb += 64) {
        const int j = jb + lane;
        const float wh2 = Wh2[j];

        // Phase A: each lane computes p for its own j, for all 4 owned rows.
        float w[4];
        #pragma unroll
        for (int q = 0; q < 4; ++q) {
            const int av = adj[(size_t)r[q] * N + j];     // coalesced 256B, HBM stream
            float s = wh1[q] + wh2;
            s = fmaxf(s, ALPHA * s);                      // LeakyReLU
            float p = __expf(s);
            p = (av > 0) ? p : 0.f;
            w[q] = p;
            den[q] += p;                                  // per-lane partial
        }

        // Phase B: broadcast each lane's p (readlane, uniform idx) and FMA
        // against coalesced Wh rows (2MB total -> L2 resident).
        const float* __restrict__ whp = Wh + (size_t)jb * FOUT + lane;
        #pragma unroll 8
        for (int jj = 0; jj < 64; ++jj) {
            const float whv = whp[(size_t)jj * FOUT];
            #pragma unroll
            for (int q = 0; q < 4; ++q) {
                acc[q] = fmaf(lane_bcast(w[q], jj), whv, acc[q]);
            }
        }
    }

    // Finish: reduce den across the wave, normalize, ELU, store.
    #pragma unroll
    for (int q = 0; q < 4; ++q) {
        float d = den[q];
        #pragma unroll
        for (int off = 32; off > 0; off >>= 1) d += __shfl_xor(d, off, 64);
        float o = acc[q] / d;
        o = (o > 0.f) ? o : (__expf(o) - 1.f);
        out[(size_t)r[q] * FOUT + lane] = o;
    }
}

extern "C" void kernel_launch(void* const* d_in, const int* in_sizes, int n_in,
                              void* d_out, int out_size, void* d_ws, size_t ws_size,
                              hipStream_t stream) {
    const float* x   = (const float*)d_in[0];   // [N, FIN]
    const int*   adj = (const int*)  d_in[1];   // [N, N]
    const float* W   = (const float*)d_in[2];   // [FIN, FOUT]
    const float* a   = (const float*)d_in[3];   // [2*FOUT, 1]
    float* out = (float*)d_out;                 // [N, FOUT]

    // workspace layout: Wh [N*FOUT] f32 | Wh1 [N] | Wh2 [N]  (~2.06 MB)
    float* Wh  = (float*)d_ws;
    float* Wh1 = Wh + (size_t)N * FOUT;
    float* Wh2 = Wh1 + N;

    gat_proj<<<N / 4, 256, 0, stream>>>(x, W, a, Wh, Wh1, Wh2);
    gat_attn<<<N / 16, 256, 0, stream>>>(adj, Wh, Wh1, Wh2, out);
}

// Round 2
// 398.190 us; speedup vs baseline: 1.9459x; 1.9459x over previous
//
#include <hip/hip_runtime.h>
#include <hip/hip_bf16.h>

#define NN 8192
#define FIN 128
#define FOUT 64
#define ALPHA 0.2f
#define CHUNK 256          // j-tile per iteration
#define BM 16              // rows per block
#define NCHUNK (NN / CHUNK)
#define PROW (CHUNK + 8)   // +8 bf16 = +16B pad: breaks 512B stride, keeps 16B align

typedef __attribute__((ext_vector_type(8))) short short8;   // 8 bf16 (4 VGPRs)
typedef __attribute__((ext_vector_type(4))) float floatx4;

static __device__ __forceinline__ ushort f2bf(float f) {
    __hip_bfloat16 h = __float2bfloat16(f);
    return __builtin_bit_cast(ushort, h);
}

// K1: WhT[f][row] = bf16(x @ W); Wh1 = Wh@a[:64]; Wh2 = Wh@a[64:]  (fp32)
// grid NN/4 x 256: wave per row, lane = f
__global__ __launch_bounds__(256) void gat_proj(const float* __restrict__ x,
                                                const float* __restrict__ W,
                                                const float* __restrict__ a,
                                                ushort* __restrict__ WhT,
                                                float* __restrict__ Wh1,
                                                float* __restrict__ Wh2) {
    const int t = threadIdx.x;
    const int f = t & 63;
    const int rl = t >> 6;
    const int row = blockIdx.x * 4 + rl;
    const float4* __restrict__ x4 = (const float4*)(x + (size_t)row * FIN);

    float acc = 0.f;
    #pragma unroll
    for (int k4 = 0; k4 < FIN / 4; ++k4) {
        float4 xv = x4[k4];
        const int k = k4 * 4;
        acc = fmaf(xv.x, W[(k + 0) * FOUT + f], acc);
        acc = fmaf(xv.y, W[(k + 1) * FOUT + f], acc);
        acc = fmaf(xv.z, W[(k + 2) * FOUT + f], acc);
        acc = fmaf(xv.w, W[(k + 3) * FOUT + f], acc);
    }
    // transposed bf16 store (scattered 2B; only 1MB total, L2 write-combines)
    WhT[(size_t)f * NN + row] = f2bf(acc);

    float s1 = acc * a[f];
    float s2 = acc * a[FOUT + f];
    #pragma unroll
    for (int off = 32; off; off >>= 1) {
        s1 += __shfl_xor(s1, off, 64);
        s2 += __shfl_xor(s2, off, 64);
    }
    if (f == 0) { Wh1[row] = s1; Wh2[row] = s2; }
}

// K2: fused masked softmax + aggregation via bf16 MFMA + ELU.
// grid NN/BM = 512 blocks x 256 threads (4 waves). Block owns 16 rows.
// Phase A: wave wv computes scores for rows wv*4..+3, thread covers 4 j (int4 adj).
// Phase B: wave wv computes f-tile [16*wv .. +15] for all 16 rows via MFMA.
__global__ __launch_bounds__(256) void gat_attn(const int* __restrict__ adj,
                                                const ushort* __restrict__ WhT,
                                                const float* __restrict__ Wh1,
                                                const float* __restrict__ Wh2,
                                                float* __restrict__ out) {
    __shared__ __align__(16) ushort P[2][BM][PROW];   // bf16 score tiles, dbuf
    __shared__ float denL[BM];

    const int t = threadIdx.x;
    const int lane = t & 63;
    const int wv = t >> 6;            // wave id 0..3
    const int row0 = blockIdx.x * BM;
    const int ln = lane & 15;
    const int quad = lane >> 4;

    const float4 wh1v = *(const float4*)(Wh1 + row0 + wv * 4);   // broadcast
    const int* __restrict__ aptr = adj + (size_t)(row0 + wv * 4) * NN + lane * 4;

    floatx4 acc = {0.f, 0.f, 0.f, 0.f};
    float den0 = 0.f, den1 = 0.f, den2 = 0.f, den3 = 0.f;

    // scores for chunk c into buffer b
    auto computeP = [&](int c, int b) {
        const int jb = c * CHUNK;
        const float4 wh2v = *(const float4*)(Wh2 + jb + lane * 4);
        const int4 av0 = *(const int4*)(aptr + (size_t)0 * NN + jb);
        const int4 av1 = *(const int4*)(aptr + (size_t)1 * NN + jb);
        const int4 av2 = *(const int4*)(aptr + (size_t)2 * NN + jb);
        const int4 av3 = *(const int4*)(aptr + (size_t)3 * NN + jb);
#define ROWP(AV, W1, DEN, II)                                              \
        {                                                                  \
            float s0 = (W1) + wh2v.x, s1 = (W1) + wh2v.y,                  \
                  s2 = (W1) + wh2v.z, s3 = (W1) + wh2v.w;                  \
            s0 = fmaxf(s0, ALPHA * s0); s1 = fmaxf(s1, ALPHA * s1);        \
            s2 = fmaxf(s2, ALPHA * s2); s3 = fmaxf(s3, ALPHA * s3);        \
            float p0 = __expf(s0), p1 = __expf(s1),                        \
                  p2 = __expf(s2), p3 = __expf(s3);                        \
            p0 = (AV.x > 0) ? p0 : 0.f; p1 = (AV.y > 0) ? p1 : 0.f;        \
            p2 = (AV.z > 0) ? p2 : 0.f; p3 = (AV.w > 0) ? p3 : 0.f;       \
            DEN += (p0 + p1) + (p2 + p3);                                  \
            ushort4 pk = make_ushort4(f2bf(p0), f2bf(p1), f2bf(p2), f2bf(p3)); \
            *(ushort4*)&P[b][wv * 4 + (II)][lane * 4] = pk;                \
        }
        ROWP(av0, wh1v.x, den0, 0)
        ROWP(av1, wh1v.y, den1, 1)
        ROWP(av2, wh1v.z, den2, 2)
        ROWP(av3, wh1v.w, den3, 3)
#undef ROWP
    };

    computeP(0, 0);
    __syncthreads();

    int pb = 0;
    for (int c = 0; c < NCHUNK; ++c) {
        if (c + 1 < NCHUNK) computeP(c + 1, pb ^ 1);   // adj HBM loads issue early

        const int jb = c * CHUNK;
        const ushort* Arow = &P[pb][ln][quad * 8];
        const ushort* Brow = WhT + (size_t)(wv * 16 + ln) * NN + jb + quad * 8;
        #pragma unroll
        for (int k0 = 0; k0 < 8; ++k0) {
            short8 af = *(const short8*)(Arow + k0 * 32);   // ds_read_b128
            short8 bf = *(const short8*)(Brow + k0 * 32);   // L2-resident 16B
            acc = __builtin_amdgcn_mfma_f32_16x16x32_bf16(af, bf, acc, 0, 0, 0);
        }
        __syncthreads();
        pb ^= 1;
    }

    // den: wave-64 reduce (all lanes of wave wv hold partials for rows wv*4..+3)
    float dsum[4] = {den0, den1, den2, den3};
    #pragma unroll
    for (int ii = 0; ii < 4; ++ii) {
        float d = dsum[ii];
        #pragma unroll
        for (int off = 32; off; off >>= 1) d += __shfl_xor(d, off, 64);
        if (lane == 0) denL[wv * 4 + ii] = d;
    }
    __syncthreads();

    // epilogue: D[m=quad*4+reg][n=lane&15] (verified C/D layout), normalize+ELU
    #pragma unroll
    for (int r = 0; r < 4; ++r) {
        const int i = quad * 4 + r;
        float o = acc[r] / denL[i];
        o = (o > 0.f) ? o : (__expf(o) - 1.f);
        out[(size_t)(row0 + i) * FOUT + wv * 16 + ln] = o;
    }
}

extern "C" void kernel_launch(void* const* d_in, const int* in_sizes, int n_in,
                              void* d_out, int out_size, void* d_ws, size_t ws_size,
                              hipStream_t stream) {
    const float* x   = (const float*)d_in[0];   // [N, FIN]
    const int*   adj = (const int*)  d_in[1];   // [N, N]
    const float* W   = (const float*)d_in[2];   // [FIN, FOUT]
    const float* a   = (const float*)d_in[3];   // [2*FOUT, 1]
    float* out = (float*)d_out;                 // [N, FOUT]

    // ws: WhT bf16 [64][8192] (1MB) | Wh1 f32 [8192] | Wh2 f32 [8192]
    ushort* WhT = (ushort*)d_ws;
    float* Wh1 = (float*)(WhT + (size_t)FOUT * NN);
    float* Wh2 = Wh1 + NN;

    gat_proj<<<NN / 4, 256, 0, stream>>>(x, W, a, WhT, Wh1, Wh2);
    gat_attn<<<NN / BM, 256, 0, stream>>>(adj, WhT, Wh1, Wh2, out);
}